// Round 1
// baseline (232688.940 us; speedup 1.0000x reference)
//
#include <hip/hip_runtime.h>

#define TT   8192
#define HD   1024
#define NBLK 256
#define NTHR 256

// fast fp32 sigmoid/tanh via v_exp_f32 (~1-2 ulp). No overflow hazards:
// exp(+inf)->inf gives sig->0 / tanh->1 cleanly.
__device__ __forceinline__ float sigf(float z) {
  return 1.0f / (1.0f + __expf(-z));
}
__device__ __forceinline__ float tanh_fast(float z) {
  float az = fabsf(z);
  float e  = __expf(2.0f * az);          // >= 1
  float t  = 1.0f - 2.0f / (e + 1.0f);
  return z < 0.0f ? -t : t;
}

#define FMA4(acc, hvv, wvv)                                      \
  acc = fmaf((hvv).x, (wvv).x, acc);                             \
  acc = fmaf((hvv).y, (wvv).y, acc);                             \
  acc = fmaf((hvv).z, (wvv).z, acc);                             \
  acc = fmaf((hvv).w, (wvv).w, acc);

extern "C" __global__ __launch_bounds__(NTHR, 1)
void lstm_persistent(const float* __restrict__ x,
                     const float* __restrict__ W_ih,
                     const float* __restrict__ W_hh,
                     const float* __restrict__ b_ih,
                     const float* __restrict__ b_hh,
                     const float* __restrict__ W_fc,
                     const float* __restrict__ b_fc,
                     float* __restrict__ out,
                     int*   __restrict__ cnt,    // [TT], zeroed by memset
                     float* __restrict__ hbuf)   // [2][HD] double buffer
{
  __shared__ float x_lds[TT];     // 32 KB: whole input sequence
  __shared__ float h_lds[HD];     //  4 KB: broadcast of h_{t-1}
  __shared__ float g_lds[16];     // [gate][unit] reduced matvec results

  const int tid  = threadIdx.x;
  const int wave = tid >> 6;      // 0..3  == gate index (i,f,g,o)
  const int lane = tid & 63;
  const int blk  = blockIdx.x;
  const int u0   = blk * 4;       // first of this block's 4 hidden units

  // ---- one-time staging -------------------------------------------------
  // x -> LDS (each block keeps the full sequence locally)
  for (int i = tid; i < TT / 4; i += NTHR)
    ((float4*)x_lds)[i] = ((const float4*)x)[i];

  // W_hh fragment -> registers. Row r_j = wave*HD + u0 + j (gate=wave,
  // unit=j). Lane covers k = m*256 + 4*lane + {0..3}, m=0..3.
  float4 w4[4][4];
#pragma unroll
  for (int j = 0; j < 4; ++j) {
    const float* wr = W_hh + (size_t)(wave * HD + u0 + j) * HD;
#pragma unroll
    for (int m = 0; m < 4; ++m)
      w4[j][m] = *((const float4*)(wr + m * 256 + lane * 4));
  }
  // W_fc fragment (same k-mapping) for the fused output dot
  float4 wfc4[4];
#pragma unroll
  for (int m = 0; m < 4; ++m)
    wfc4[m] = *((const float4*)(W_fc + m * 256 + lane * 4));
  const float bfc_val = b_fc[0];

  // per-unit input-gate coefficients for the nonlinearity lanes
  float wih_g[4] = {0.f, 0.f, 0.f, 0.f};
  float bs_g[4]  = {0.f, 0.f, 0.f, 0.f};
  if (wave == 0 && lane < 4) {
#pragma unroll
    for (int g = 0; g < 4; ++g) {
      int r = g * HD + u0 + lane;
      wih_g[g] = W_ih[r];
      bs_g[g]  = b_ih[r] + b_hh[r];
    }
  }
  float c_state = 0.0f;           // cell state, register-resident
  __syncthreads();                // x_lds ready

  float4 h4[4];

  // ---- the sequential scan ---------------------------------------------
  for (int t = 0; t < TT; ++t) {
    float acc0 = 0.f, acc1 = 0.f, acc2 = 0.f, acc3 = 0.f;

    if (t > 0) {
      const int tm1 = t - 1;
      // wait until every block published h_{t-1}
      while (__hip_atomic_load(cnt + tm1, __ATOMIC_RELAXED,
                               __HIP_MEMORY_SCOPE_AGENT) < NBLK)
        __builtin_amdgcn_s_sleep(1);
      __builtin_amdgcn_fence(__ATOMIC_ACQUIRE, "agent");

      // cooperative load h_{t-1} -> LDS (1 float4 per thread, coalesced)
      const float4* hsrc = (const float4*)(hbuf + (tm1 & 1) * HD);
      ((float4*)h_lds)[tid] = hsrc[tid];
      __syncthreads();

      // per-lane h fragments (conflict-free b128 reads)
#pragma unroll
      for (int m = 0; m < 4; ++m)
        h4[m] = *((const float4*)(h_lds + m * 256 + lane * 4));

      // 16-row mat-vec: 64 FMAs, 4 independent chains
#pragma unroll
      for (int m = 0; m < 4; ++m) {
        float4 hm = h4[m];
        FMA4(acc0, hm, w4[0][m]);
        FMA4(acc1, hm, w4[1][m]);
        FMA4(acc2, hm, w4[2][m]);
        FMA4(acc3, hm, w4[3][m]);
      }
    }

    // butterfly reduce the 4 row partials across the wave
#pragma unroll
    for (int s = 1; s < 64; s <<= 1) {
      acc0 += __shfl_xor(acc0, s);
      acc1 += __shfl_xor(acc1, s);
      acc2 += __shfl_xor(acc2, s);
      acc3 += __shfl_xor(acc3, s);
    }
    if (lane == 0) {
      g_lds[wave * 4 + 0] = acc0;
      g_lds[wave * 4 + 1] = acc1;
      g_lds[wave * 4 + 2] = acc2;
      g_lds[wave * 4 + 3] = acc3;
    }
    __syncthreads();

    // gate nonlinearities + state update: wave 0, lanes 0..3 (unit = lane)
    if (wave == 0 && lane < 4) {
      float xt = x_lds[t];
      float gi = g_lds[0 * 4 + lane] + fmaf(xt, wih_g[0], bs_g[0]);
      float gf = g_lds[1 * 4 + lane] + fmaf(xt, wih_g[1], bs_g[1]);
      float gg = g_lds[2 * 4 + lane] + fmaf(xt, wih_g[2], bs_g[2]);
      float go = g_lds[3 * 4 + lane] + fmaf(xt, wih_g[3], bs_g[3]);
      c_state  = sigf(gf) * c_state + sigf(gi) * tanh_fast(gg);
      float hn = sigf(go) * tanh_fast(c_state);
      __hip_atomic_store(hbuf + (t & 1) * HD + u0 + lane, hn,
                         __ATOMIC_RELAXED, __HIP_MEMORY_SCOPE_AGENT);
    }
    if (wave == 0) {
      __builtin_amdgcn_fence(__ATOMIC_RELEASE, "agent");
      if (lane == 0)
        __hip_atomic_fetch_add(cnt + t, 1, __ATOMIC_RELAXED,
                               __HIP_MEMORY_SCOPE_AGENT);
    }

    // fused output projection for step t-1, off the critical path:
    // block (t & 255), wave 1, after the signal was sent.
    if (t > 0 && wave == 1 && blk == (t & 255)) {
      float p = 0.f;
#pragma unroll
      for (int m = 0; m < 4; ++m) { FMA4(p, h4[m], wfc4[m]); }
#pragma unroll
      for (int s = 1; s < 64; s <<= 1) p += __shfl_xor(p, s);
      if (lane == 0) out[t - 1] = p + bfc_val;
    }
  }

  // ---- epilogue: out[T-1] -----------------------------------------------
  if (blk == 0) {
    const int last = TT - 1;
    while (__hip_atomic_load(cnt + last, __ATOMIC_RELAXED,
                             __HIP_MEMORY_SCOPE_AGENT) < NBLK)
      __builtin_amdgcn_s_sleep(1);
    __builtin_amdgcn_fence(__ATOMIC_ACQUIRE, "agent");
    if (wave == 1) {
      float p = 0.f;
#pragma unroll
      for (int m = 0; m < 4; ++m) {
        float4 hm = *((const float4*)(hbuf + HD + m * 256 + lane * 4));
        FMA4(p, hm, wfc4[m]);
      }
#pragma unroll
      for (int s = 1; s < 64; s <<= 1) p += __shfl_xor(p, s);
      if (lane == 0) out[last] = p + bfc_val;
    }
  }
}

extern "C" void kernel_launch(void* const* d_in, const int* in_sizes, int n_in,
                              void* d_out, int out_size, void* d_ws, size_t ws_size,
                              hipStream_t stream) {
  const float* x   = (const float*)d_in[0];
  const float* Wih = (const float*)d_in[1];
  const float* Whh = (const float*)d_in[2];
  const float* bih = (const float*)d_in[3];
  const float* bhh = (const float*)d_in[4];
  const float* Wfc = (const float*)d_in[5];
  const float* bfc = (const float*)d_in[6];
  float* out = (float*)d_out;

  int*   cnt  = (int*)d_ws;                              // TT ints
  float* hbuf = (float*)((char*)d_ws + TT * sizeof(int)); // 2*HD floats

  hipMemsetAsync(d_ws, 0, TT * sizeof(int), stream);
  hipLaunchKernelGGL(lstm_persistent, dim3(NBLK), dim3(NTHR), 0, stream,
                     x, Wih, Whh, bih, bhh, Wfc, bfc, out, cnt, hbuf);
}

// Round 2
// 35346.735 us; speedup vs baseline: 6.5830x; 6.5830x over previous
//
#include <hip/hip_runtime.h>

#define TT   8192
#define HD   1024
#define NBLK 256
#define NTHR 256

typedef float f32x4 __attribute__((ext_vector_type(4)));
typedef int   i32x4 __attribute__((ext_vector_type(4)));

// ---- LLC-coherent (cross-XCD) accesses: sc0 sc1 bypass L1+L2, no fences ----
__device__ __forceinline__ f32x4 llc_load4f(const float* p) {
  f32x4 r;
  asm volatile("global_load_dwordx4 %0, %1, off sc0 sc1\n\ts_waitcnt vmcnt(0)"
               : "=v"(r) : "v"(p) : "memory");
  return r;
}
__device__ __forceinline__ i32x4 llc_load4i(const int* p) {
  i32x4 r;
  asm volatile("global_load_dwordx4 %0, %1, off sc0 sc1\n\ts_waitcnt vmcnt(0)"
               : "=v"(r) : "v"(p) : "memory");
  return r;
}
__device__ __forceinline__ void llc_store1f(float* p, float v) {
  asm volatile("global_store_dword %0, %1, off sc0 sc1" :: "v"(p), "v"(v) : "memory");
}
__device__ __forceinline__ void llc_store1i(int* p, int v) {
  asm volatile("global_store_dword %0, %1, off sc0 sc1" :: "v"(p), "v"(v) : "memory");
}
__device__ __forceinline__ void vm_drain() {
  asm volatile("s_waitcnt vmcnt(0)" ::: "memory");
}

__device__ __forceinline__ float sigf(float z) {
  return 1.0f / (1.0f + __expf(-z));
}
__device__ __forceinline__ float tanh_fast(float z) {
  float az = fabsf(z);
  float e  = __expf(2.0f * az);          // >= 1
  float t  = 1.0f - 2.0f / (e + 1.0f);
  return z < 0.0f ? -t : t;
}

#define FMA4(acc, hvv, wvv)                                      \
  acc = fmaf((hvv).x, (wvv).x, acc);                             \
  acc = fmaf((hvv).y, (wvv).y, acc);                             \
  acc = fmaf((hvv).z, (wvv).z, acc);                             \
  acc = fmaf((hvv).w, (wvv).w, acc);

extern "C" __global__ __launch_bounds__(NTHR, 1)
void lstm_persistent(const float* __restrict__ x,
                     const float* __restrict__ W_ih,
                     const float* __restrict__ W_hh,
                     const float* __restrict__ b_ih,
                     const float* __restrict__ b_hh,
                     const float* __restrict__ W_fc,
                     const float* __restrict__ b_fc,
                     float* __restrict__ out,
                     int*   __restrict__ flags,  // [2][NBLK], zeroed by memset
                     float* __restrict__ hbuf)   // [2][HD] double buffer
{
  __shared__ float x_lds[TT];     // 32 KB: whole input sequence
  __shared__ float h_lds[HD];     //  4 KB: broadcast of h_{t-1}
  __shared__ float g_lds[16];     // [gate][unit] reduced matvec results

  const int tid  = threadIdx.x;
  const int wave = tid >> 6;      // 0..3  == gate index (i,f,g,o)
  const int lane = tid & 63;
  const int blk  = blockIdx.x;
  const int u0   = blk * 4;       // first of this block's 4 hidden units

  // ---- one-time staging -------------------------------------------------
  for (int i = tid; i < TT / 4; i += NTHR)
    ((float4*)x_lds)[i] = ((const float4*)x)[i];

  // W_hh fragment -> registers. Row r_j = wave*HD + u0 + j. Lane covers
  // k = m*256 + 4*lane + {0..3}, m=0..3.
  float4 w4[4][4];
#pragma unroll
  for (int j = 0; j < 4; ++j) {
    const float* wr = W_hh + (size_t)(wave * HD + u0 + j) * HD;
#pragma unroll
    for (int m = 0; m < 4; ++m)
      w4[j][m] = *((const float4*)(wr + m * 256 + lane * 4));
  }
  float4 wfc4[4];
#pragma unroll
  for (int m = 0; m < 4; ++m)
    wfc4[m] = *((const float4*)(W_fc + m * 256 + lane * 4));
  const float bfc_val = b_fc[0];

  float wih_g[4] = {0.f, 0.f, 0.f, 0.f};
  float bs_g[4]  = {0.f, 0.f, 0.f, 0.f};
  if (wave == 0 && lane < 4) {
#pragma unroll
    for (int g = 0; g < 4; ++g) {
      int r = g * HD + u0 + lane;
      wih_g[g] = W_ih[r];
      bs_g[g]  = b_ih[r] + b_hh[r];
    }
  }
  float c_state = 0.0f;
  __syncthreads();                // x_lds ready

  float4 h4[4];

  // ---- the sequential scan ---------------------------------------------
  for (int t = 0; t < TT; ++t) {
    float acc0 = 0.f, acc1 = 0.f, acc2 = 0.f, acc3 = 0.f;

    if (t > 0) {
      const int pm = (t - 1) & 1;
      // wave 0 polls all 256 flags (4 per lane, one dwordx4 from LLC);
      // flag value for step t-1 is t.  Wait-free: no RMW, no fence.
      if (wave == 0) {
        const int* fl = flags + pm * NBLK + lane * 4;
        i32x4 f;
        do {
          f = llc_load4i(fl);
        } while (!__all(f.x >= t && f.y >= t && f.z >= t && f.w >= t));
      }
      __syncthreads();

      // cooperative load h_{t-1} from LLC -> LDS (1 float4 per thread)
      f32x4 hv = llc_load4f(hbuf + pm * HD + tid * 4);
      ((f32x4*)h_lds)[tid] = hv;
      __syncthreads();

#pragma unroll
      for (int m = 0; m < 4; ++m)
        h4[m] = *((const float4*)(h_lds + m * 256 + lane * 4));

#pragma unroll
      for (int m = 0; m < 4; ++m) {
        float4 hm = h4[m];
        FMA4(acc0, hm, w4[0][m]);
        FMA4(acc1, hm, w4[1][m]);
        FMA4(acc2, hm, w4[2][m]);
        FMA4(acc3, hm, w4[3][m]);
      }
    }

    // butterfly reduce the 4 row partials across the wave
#pragma unroll
    for (int s = 1; s < 64; s <<= 1) {
      acc0 += __shfl_xor(acc0, s);
      acc1 += __shfl_xor(acc1, s);
      acc2 += __shfl_xor(acc2, s);
      acc3 += __shfl_xor(acc3, s);
    }
    if (lane == 0) {
      g_lds[wave * 4 + 0] = acc0;
      g_lds[wave * 4 + 1] = acc1;
      g_lds[wave * 4 + 2] = acc2;
      g_lds[wave * 4 + 3] = acc3;
    }
    __syncthreads();

    // gate nonlinearities + state update: wave 0, lanes 0..3 (unit = lane)
    if (wave == 0) {
      if (lane < 4) {
        float xt = x_lds[t];
        float gi = g_lds[0 * 4 + lane] + fmaf(xt, wih_g[0], bs_g[0]);
        float gf = g_lds[1 * 4 + lane] + fmaf(xt, wih_g[1], bs_g[1]);
        float gg = g_lds[2 * 4 + lane] + fmaf(xt, wih_g[2], bs_g[2]);
        float go = g_lds[3 * 4 + lane] + fmaf(xt, wih_g[3], bs_g[3]);
        c_state  = sigf(gf) * c_state + sigf(gi) * tanh_fast(gg);
        float hn = sigf(go) * tanh_fast(c_state);
        llc_store1f(hbuf + (t & 1) * HD + u0 + lane, hn);
      }
      vm_drain();                         // h stores ack'd at LLC
      if (lane == 0)
        llc_store1i(flags + (t & 1) * NBLK + blk, t + 1);   // signal
    }

    // fused output projection for step t-1, off the critical path
    if (t > 0 && wave == 1 && blk == (t & 255)) {
      float p = 0.f;
#pragma unroll
      for (int m = 0; m < 4; ++m) { FMA4(p, h4[m], wfc4[m]); }
#pragma unroll
      for (int s = 1; s < 64; s <<= 1) p += __shfl_xor(p, s);
      if (lane == 0) out[t - 1] = p + bfc_val;
    }
  }

  // ---- epilogue: out[T-1] -----------------------------------------------
  if (blk == 0) {
    if (wave == 0) {
      const int* fl = flags + ((TT - 1) & 1) * NBLK + lane * 4;
      i32x4 f;
      do {
        f = llc_load4i(fl);
      } while (!__all(f.x >= TT && f.y >= TT && f.z >= TT && f.w >= TT));
    }
    __syncthreads();
    if (wave == 1) {
      float p = 0.f;
#pragma unroll
      for (int m = 0; m < 4; ++m) {
        f32x4 hm = llc_load4f(hbuf + ((TT - 1) & 1) * HD + m * 256 + lane * 4);
        float4 hm4 = *(float4*)&hm;
        FMA4(p, hm4, wfc4[m]);
      }
#pragma unroll
      for (int s = 1; s < 64; s <<= 1) p += __shfl_xor(p, s);
      if (lane == 0) out[TT - 1] = p + bfc_val;
    }
  }
}

extern "C" void kernel_launch(void* const* d_in, const int* in_sizes, int n_in,
                              void* d_out, int out_size, void* d_ws, size_t ws_size,
                              hipStream_t stream) {
  const float* x   = (const float*)d_in[0];
  const float* Wih = (const float*)d_in[1];
  const float* Whh = (const float*)d_in[2];
  const float* bih = (const float*)d_in[3];
  const float* bhh = (const float*)d_in[4];
  const float* Wfc = (const float*)d_in[5];
  const float* bfc = (const float*)d_in[6];
  float* out = (float*)d_out;

  int*   flags = (int*)d_ws;                                   // 2*NBLK ints
  float* hbuf  = (float*)((char*)d_ws + 2 * NBLK * sizeof(int)); // 2*HD floats

  hipMemsetAsync(d_ws, 0, 2 * NBLK * sizeof(int), stream);
  hipLaunchKernelGGL(lstm_persistent, dim3(NBLK), dim3(NTHR), 0, stream,
                     x, Wih, Whh, bih, bhh, Wfc, bfc, out, flags, hbuf);
}

// Round 3
// 32956.982 us; speedup vs baseline: 7.0604x; 1.0725x over previous
//
#include <hip/hip_runtime.h>

#define TT   8192
#define HD   1024
#define NBLK 256
#define NTHR 256

typedef float f32x4 __attribute__((ext_vector_type(4)));
typedef int   i32x4 __attribute__((ext_vector_type(4)));
typedef int   i32x2 __attribute__((ext_vector_type(2)));

// ---- LLC-coherent accesses (sc0 sc1 = bypass L1+L2, coherent at MALL) ----
// Two dwordx4 loads + single drain in ONE asm block so the compiler can't
// schedule a use between load and waitcnt.
__device__ __forceinline__ void llc_load_pair(const unsigned* p, i32x4& a, i32x4& b) {
  asm volatile("global_load_dwordx4 %0, %2, off sc0 sc1\n\t"
               "global_load_dwordx4 %1, %3, off sc0 sc1\n\t"
               "s_waitcnt vmcnt(0)"
               : "=&v"(a), "=&v"(b)
               : "v"(p), "v"(p + 4)
               : "memory");
}
__device__ __forceinline__ void llc_store2(unsigned* p, unsigned lo, unsigned hi) {
  i32x2 v; v.x = (int)lo; v.y = (int)hi;
  asm volatile("global_store_dwordx2 %0, %1, off sc0 sc1"
               :: "v"(p), "v"(v) : "memory");
}

__device__ __forceinline__ float sigf(float z) {
  return 1.0f / (1.0f + __expf(-z));
}
__device__ __forceinline__ float tanh_fast(float z) {
  float az = fabsf(z);
  float e  = __expf(2.0f * az);          // >= 1
  float t  = 1.0f - 2.0f / (e + 1.0f);
  return z < 0.0f ? -t : t;
}

#define FMA4(acc, hvv, wvv)                                      \
  acc = fmaf((hvv).x, (wvv).x, acc);                             \
  acc = fmaf((hvv).y, (wvv).y, acc);                             \
  acc = fmaf((hvv).z, (wvv).z, acc);                             \
  acc = fmaf((hvv).w, (wvv).w, acc);

// hbuf layout: unsigned[2][HD][2] = {value_bits, tag}; tag for h produced at
// step t is t+1.  Consumer at step t polls buffer (t-1)&1 for tag == t.
extern "C" __global__ __launch_bounds__(NTHR, 1)
void lstm_persistent(const float* __restrict__ x,
                     const float* __restrict__ W_ih,
                     const float* __restrict__ W_hh,
                     const float* __restrict__ b_ih,
                     const float* __restrict__ b_hh,
                     const float* __restrict__ W_fc,
                     const float* __restrict__ b_fc,
                     float* __restrict__ out,
                     unsigned* __restrict__ hbuf)
{
  __shared__ float x_lds[TT];     // 32 KB: whole input sequence
  __shared__ float h_lds[HD];     //  4 KB: broadcast of h_{t-1}

  const int tid  = threadIdx.x;
  const int wave = tid >> 6;      // wave = this block's hidden-unit offset
  const int lane = tid & 63;
  const int g    = lane >> 4;     // gate 0..3 (i,f,g,o)
  const int kc   = lane & 15;     // k-chunk within the 1024-dot
  const int blk  = blockIdx.x;
  const int u0   = blk * 4;
  const int unit = u0 + wave;     // this wave's hidden unit

  // ---- one-time staging -------------------------------------------------
  for (int i = tid; i < TT / 4; i += NTHR)
    ((float4*)x_lds)[i] = ((const float4*)x)[i];

  // W_hh row (gate g, unit) — lane covers k = m*64 + kc*4 + {0..3}
  float4 w4[16];
  {
    const float* wr = W_hh + (size_t)(g * HD + unit) * HD + kc * 4;
#pragma unroll
    for (int m = 0; m < 16; ++m)
      w4[m] = *((const float4*)(wr + m * 64));
  }
  // W_fc fragment (old 64-lane k-split) for the fused output dot (wave 1)
  float4 wfc4[4];
#pragma unroll
  for (int m = 0; m < 4; ++m)
    wfc4[m] = *((const float4*)(W_fc + m * 256 + lane * 4));
  const float bfc_val = b_fc[0];

  // lane 0 of each wave owns the unit's gates/state
  float wih_g[4], bs_g[4];
#pragma unroll
  for (int q = 0; q < 4; ++q) {
    int r = q * HD + unit;
    wih_g[q] = W_ih[r];
    bs_g[q]  = b_ih[r] + b_hh[r];
  }
  float c_state = 0.0f;
  __syncthreads();                // x_lds ready

  // ---- the sequential scan: ONE barrier per step ------------------------
  for (int t = 0; t < TT; ++t) {
    const bool doproj = (t > 0) && (wave == 1) && (blk == (t & 255));
    float accs = 0.0f;
    float4 hp4[4];

    if (t > 0) {
      // poll own 4 tagged pairs (32 B) until tags == t, then stage to LDS
      const unsigned* src = hbuf + ((size_t)((t - 1) & 1) * HD + tid * 4) * 2;
      i32x4 A, B;
      do {
        llc_load_pair(src, A, B);
      } while (!(A.y == t && A.w == t && B.y == t && B.w == t));
      float4 hv;
      hv.x = __int_as_float(A.x); hv.y = __int_as_float(A.z);
      hv.z = __int_as_float(B.x); hv.w = __int_as_float(B.z);
      ((float4*)h_lds)[tid] = hv;
      __syncthreads();

      // fragments + 64 FMAs (4 independent sub-chains)
      const float* hp = h_lds + kc * 4;
      float s0 = 0.f, s1 = 0.f, s2 = 0.f, s3 = 0.f;
#pragma unroll
      for (int mb = 0; mb < 4; ++mb) {
        float4 ha = *((const float4*)(hp + (mb * 4 + 0) * 64));
        float4 hb = *((const float4*)(hp + (mb * 4 + 1) * 64));
        float4 hc = *((const float4*)(hp + (mb * 4 + 2) * 64));
        float4 hd = *((const float4*)(hp + (mb * 4 + 3) * 64));
        FMA4(s0, ha, w4[mb * 4 + 0]);
        FMA4(s1, hb, w4[mb * 4 + 1]);
        FMA4(s2, hc, w4[mb * 4 + 2]);
        FMA4(s3, hd, w4[mb * 4 + 3]);
      }
      accs = (s0 + s1) + (s2 + s3);

      // wave 1 of the projecting block snapshots h_{t-1} fragments now
      // (h_lds cannot be overwritten until this block's own h-stores land,
      //  which are sequentially after this read)
      if (doproj) {
#pragma unroll
        for (int m = 0; m < 4; ++m)
          hp4[m] = *((const float4*)(h_lds + m * 256 + lane * 4));
      }
    }

    // 4-round butterfly over kc: every lane in a gate-group gets the row sum
#pragma unroll
    for (int s = 1; s < 16; s <<= 1)
      accs += __shfl_xor(accs, s);

    // gather the 4 gate sums into lane 0 (one per wave)
    float gi = __shfl(accs, 0);
    float gf = __shfl(accs, 16);
    float gg = __shfl(accs, 32);
    float go = __shfl(accs, 48);

    if (lane == 0) {
      float xt = x_lds[t];
      gi += fmaf(xt, wih_g[0], bs_g[0]);
      gf += fmaf(xt, wih_g[1], bs_g[1]);
      gg += fmaf(xt, wih_g[2], bs_g[2]);
      go += fmaf(xt, wih_g[3], bs_g[3]);
      c_state  = sigf(gf) * c_state + sigf(gi) * tanh_fast(gg);
      float hn = sigf(go) * tanh_fast(c_state);
      llc_store2(hbuf + ((size_t)(t & 1) * HD + unit) * 2,
                 __float_as_uint(hn), (unsigned)(t + 1));  // fire & forget
    }

    // fused output projection for step t-1 (register-only, off crit path)
    if (doproj) {
      float p = 0.f;
#pragma unroll
      for (int m = 0; m < 4; ++m) { FMA4(p, hp4[m], wfc4[m]); }
#pragma unroll
      for (int s = 1; s < 64; s <<= 1) p += __shfl_xor(p, s);
      if (lane == 0) out[t - 1] = p + bfc_val;
    }
  }

  // ---- epilogue: out[TT-1] ----------------------------------------------
  if (blk == 0) {
    const unsigned* src = hbuf + ((size_t)((TT - 1) & 1) * HD + tid * 4) * 2;
    i32x4 A, B;
    do {
      llc_load_pair(src, A, B);
    } while (!(A.y == TT && A.w == TT && B.y == TT && B.w == TT));
    float4 hv;
    hv.x = __int_as_float(A.x); hv.y = __int_as_float(A.z);
    hv.z = __int_as_float(B.x); hv.w = __int_as_float(B.z);
    ((float4*)h_lds)[tid] = hv;
    __syncthreads();
    if (wave == 1) {
      float p = 0.f;
#pragma unroll
      for (int m = 0; m < 4; ++m) {
        float4 hm = *((const float4*)(h_lds + m * 256 + lane * 4));
        FMA4(p, hm, wfc4[m]);
      }
#pragma unroll
      for (int s = 1; s < 64; s <<= 1) p += __shfl_xor(p, s);
      if (lane == 0) out[TT - 1] = p + bfc_val;
    }
  }
}

extern "C" void kernel_launch(void* const* d_in, const int* in_sizes, int n_in,
                              void* d_out, int out_size, void* d_ws, size_t ws_size,
                              hipStream_t stream) {
  const float* x   = (const float*)d_in[0];
  const float* Wih = (const float*)d_in[1];
  const float* Whh = (const float*)d_in[2];
  const float* bih = (const float*)d_in[3];
  const float* bhh = (const float*)d_in[4];
  const float* Wfc = (const float*)d_in[5];
  const float* bfc = (const float*)d_in[6];
  float* out = (float*)d_out;

  unsigned* hbuf = (unsigned*)d_ws;   // [2][HD][2] = 16 KB tagged h

  hipMemsetAsync(d_ws, 0, 2 * HD * 2 * sizeof(unsigned), stream);
  hipLaunchKernelGGL(lstm_persistent, dim3(NBLK), dim3(NTHR), 0, stream,
                     x, Wih, Whh, bih, bhh, Wfc, bfc, out, hbuf);
}

// Round 5
// 23894.814 us; speedup vs baseline: 9.7381x; 1.3793x over previous
//
#include <hip/hip_runtime.h>

#define TT   8192
#define HD   1024
#define NBLK 256
#define NTHR 256
#define NREP 8      // flag replicas, one 64B line each

typedef float f32x4 __attribute__((ext_vector_type(4)));
typedef int   i32x4 __attribute__((ext_vector_type(4)));
typedef int   i32x2 __attribute__((ext_vector_type(2)));

// ---- LLC-coherent accesses (sc0 sc1 = bypass L1+L2, coherent at MALL) ----
__device__ __forceinline__ void llc_load_pair(const unsigned* p, i32x4& a, i32x4& b) {
  asm volatile("global_load_dwordx4 %0, %2, off sc0 sc1\n\t"
               "global_load_dwordx4 %1, %3, off sc0 sc1\n\t"
               "s_waitcnt vmcnt(0)"
               : "=&v"(a), "=&v"(b)
               : "v"(p), "v"(p + 4)
               : "memory");
}
__device__ __forceinline__ unsigned llc_load1(const unsigned* p) {
  unsigned r;
  asm volatile("global_load_dword %0, %1, off sc0 sc1\n\ts_waitcnt vmcnt(0)"
               : "=v"(r) : "v"(p) : "memory");
  return r;
}
__device__ __forceinline__ void llc_store2(unsigned* p, unsigned lo, unsigned hi) {
  i32x2 v; v.x = (int)lo; v.y = (int)hi;
  asm volatile("global_store_dwordx2 %0, %1, off sc0 sc1"
               :: "v"(p), "v"(v) : "memory");
}
__device__ __forceinline__ void llc_store1(unsigned* p, unsigned v) {
  asm volatile("global_store_dword %0, %1, off sc0 sc1"
               :: "v"(p), "v"(v) : "memory");
}

__device__ __forceinline__ float sigf(float z) {
  return 1.0f / (1.0f + __expf(-z));
}
__device__ __forceinline__ float tanh_fast(float z) {
  float az = fabsf(z);
  float e  = __expf(2.0f * az);          // >= 1
  float t  = 1.0f - 2.0f / (e + 1.0f);
  return z < 0.0f ? -t : t;
}

#define FMA4(acc, hvv, wvv)                                      \
  acc = fmaf((hvv).x, (wvv).x, acc);                             \
  acc = fmaf((hvv).y, (wvv).y, acc);                             \
  acc = fmaf((hvv).z, (wvv).z, acc);                             \
  acc = fmaf((hvv).w, (wvv).w, acc);

// hbuf: unsigned[2][HD][2] {value_bits, tag}; tag for h of step t is t+1.
// flag: unsigned[NREP*16]; replica r at flag[r*16]. flag >= t+1 <=> step-t
// data complete at MALL (written by block 0 after it verified all tags).
extern "C" __global__ __launch_bounds__(NTHR, 1)
void lstm_persistent(const float* __restrict__ x,
                     const float* __restrict__ W_ih,
                     const float* __restrict__ W_hh,
                     const float* __restrict__ b_ih,
                     const float* __restrict__ b_hh,
                     const float* __restrict__ W_fc,
                     const float* __restrict__ b_fc,
                     float* __restrict__ out,
                     unsigned* __restrict__ flag,
                     unsigned* __restrict__ hbuf)
{
  __shared__ float x_lds[TT];     // 32 KB: whole input sequence
  __shared__ float h_lds[HD];     //  4 KB: broadcast of h_{t-1}

  const int tid  = threadIdx.x;
  const int wave = tid >> 6;
  const int lane = tid & 63;
  const int g    = lane >> 4;     // gate 0..3 (i,f,g,o)
  const int kc   = lane & 15;     // k-chunk within the 1024-dot
  const int blk  = blockIdx.x;
  const int unit = blk * 4 + wave;

  // ---- one-time staging -------------------------------------------------
  for (int i = tid; i < TT / 4; i += NTHR)
    ((float4*)x_lds)[i] = ((const float4*)x)[i];

  // W_hh row (gate g, unit) — lane covers k = m*64 + kc*4 + {0..3}
  float4 w4[16];
  {
    const float* wr = W_hh + (size_t)(g * HD + unit) * HD + kc * 4;
#pragma unroll
    for (int m = 0; m < 16; ++m)
      w4[m] = *((const float4*)(wr + m * 64));
  }
  float4 wfc4[4];
#pragma unroll
  for (int m = 0; m < 4; ++m)
    wfc4[m] = *((const float4*)(W_fc + m * 256 + lane * 4));
  const float bfc_val = b_fc[0];

  float wih_g[4], bs_g[4];
#pragma unroll
  for (int q = 0; q < 4; ++q) {
    int r = q * HD + unit;
    wih_g[q] = W_ih[r];
    bs_g[q]  = b_ih[r] + b_hh[r];
  }
  float c_state = 0.0f;
  __syncthreads();                // x_lds ready

  const unsigned* flag_mine = flag + ((blk & (NREP - 1)) << 4);

  // ---- the sequential scan ---------------------------------------------
  for (int t = 0; t < TT; ++t) {
    const bool doproj = (t > 0) && (wave == 1) && (blk == (t & 255));
    float accs = 0.0f;
    float4 hp4[4];

    if (t > 0) {
      if (blk != 0) {
        // 1) cheap gate: poll the replica flag (1 coalesced tx per wave)
        while (llc_load1(flag_mine) < (unsigned)t) { }
        // 2) one tag-verified data read (hot in MALL; ~1 iteration)
        const unsigned* src = hbuf + ((size_t)((t - 1) & 1) * HD + tid * 4) * 2;
        i32x4 A, B;
        do {
          llc_load_pair(src, A, B);
        } while (!(A.y == t && A.w == t && B.y == t && B.w == t));
        float4 hv;
        hv.x = __int_as_float(A.x); hv.y = __int_as_float(A.z);
        hv.z = __int_as_float(B.x); hv.w = __int_as_float(B.z);
        ((float4*)h_lds)[tid] = hv;
        __syncthreads();
      }
      // blk 0: h_lds was staged+synced at the end of step t-1 (sequencer)

      // fragments + 64 FMAs (4 independent sub-chains)
      const float* hp = h_lds + kc * 4;
      float s0 = 0.f, s1 = 0.f, s2 = 0.f, s3 = 0.f;
#pragma unroll
      for (int mb = 0; mb < 4; ++mb) {
        float4 ha = *((const float4*)(hp + (mb * 4 + 0) * 64));
        float4 hb = *((const float4*)(hp + (mb * 4 + 1) * 64));
        float4 hc = *((const float4*)(hp + (mb * 4 + 2) * 64));
        float4 hd = *((const float4*)(hp + (mb * 4 + 3) * 64));
        FMA4(s0, ha, w4[mb * 4 + 0]);
        FMA4(s1, hb, w4[mb * 4 + 1]);
        FMA4(s2, hc, w4[mb * 4 + 2]);
        FMA4(s3, hd, w4[mb * 4 + 3]);
      }
      accs = (s0 + s1) + (s2 + s3);

      if (doproj) {
#pragma unroll
        for (int m = 0; m < 4; ++m)
          hp4[m] = *((const float4*)(h_lds + m * 256 + lane * 4));
      }
    }

    // 4-round butterfly over kc: every lane in a gate-group gets the row sum
#pragma unroll
    for (int s = 1; s < 16; s <<= 1)
      accs += __shfl_xor(accs, s);

    float gi = __shfl(accs, 0);
    float gf = __shfl(accs, 16);
    float gg = __shfl(accs, 32);
    float go = __shfl(accs, 48);

    if (lane == 0) {
      float xt = x_lds[t];
      gi += fmaf(xt, wih_g[0], bs_g[0]);
      gf += fmaf(xt, wih_g[1], bs_g[1]);
      gg += fmaf(xt, wih_g[2], bs_g[2]);
      go += fmaf(xt, wih_g[3], bs_g[3]);
      c_state  = sigf(gf) * c_state + sigf(gi) * tanh_fast(gg);
      float hn = sigf(go) * tanh_fast(c_state);
      llc_store2(hbuf + ((size_t)(t & 1) * HD + unit) * 2,
                 __float_as_uint(hn), (unsigned)(t + 1));  // fire & forget
    }

    // ---- sequencer: block 0 detects completion, restages, raises flag ---
    if (blk == 0) {
      __syncthreads();            // all waves done with h_lds; stores issued
      const unsigned* src = hbuf + ((size_t)(t & 1) * HD + tid * 4) * 2;
      i32x4 A, B;
      do {
        llc_load_pair(src, A, B);
      } while (!(A.y == t + 1 && A.w == t + 1 && B.y == t + 1 && B.w == t + 1));
      float4 hv;
      hv.x = __int_as_float(A.x); hv.y = __int_as_float(A.z);
      hv.z = __int_as_float(B.x); hv.w = __int_as_float(B.z);
      ((float4*)h_lds)[tid] = hv;           // stage for OUR step t+1
      __syncthreads();                      // all tags seen before flagging
      if (tid < NREP)
        llc_store1(flag + (tid << 4), (unsigned)(t + 1));
    }

    // fused output projection for step t-1 (register-only, off crit path)
    if (doproj) {
      float p = 0.f;
#pragma unroll
      for (int m = 0; m < 4; ++m) { FMA4(p, hp4[m], wfc4[m]); }
#pragma unroll
      for (int s = 1; s < 64; s <<= 1) p += __shfl_xor(p, s);
      if (lane == 0) out[t - 1] = p + bfc_val;
    }
  }

  // ---- epilogue: out[TT-1] — block 0 already holds h_{TT-1} in h_lds ----
  if (blk == 0 && wave == 1) {
    float p = 0.f;
#pragma unroll
    for (int m = 0; m < 4; ++m) {
      float4 hm = *((const float4*)(h_lds + m * 256 + lane * 4));
      FMA4(p, hm, wfc4[m]);
    }
#pragma unroll
    for (int s = 1; s < 64; s <<= 1) p += __shfl_xor(p, s);
    if (lane == 0) out[TT - 1] = p + bfc_val;
  }
}

extern "C" void kernel_launch(void* const* d_in, const int* in_sizes, int n_in,
                              void* d_out, int out_size, void* d_ws, size_t ws_size,
                              hipStream_t stream) {
  const float* x   = (const float*)d_in[0];
  const float* Wih = (const float*)d_in[1];
  const float* Whh = (const float*)d_in[2];
  const float* bih = (const float*)d_in[3];
  const float* bhh = (const float*)d_in[4];
  const float* Wfc = (const float*)d_in[5];
  const float* bfc = (const float*)d_in[6];
  float* out = (float*)d_out;

  // ws layout: [flag: NREP lines of 64 B][hbuf: 2*HD tagged pairs = 16 KB]
  unsigned* flag = (unsigned*)d_ws;
  unsigned* hbuf = flag + NREP * 16;
  size_t init_bytes = (NREP * 16 + 2 * HD * 2) * sizeof(unsigned);

  // zeros: tag 0 never equals t+1 (>=1); flag 0 < any t
  hipMemsetAsync(d_ws, 0, init_bytes, stream);
  hipLaunchKernelGGL(lstm_persistent, dim3(NBLK), dim3(NTHR), 0, stream,
                     x, Wih, Whh, bih, bhh, Wfc, bfc, out, flag, hbuf);
}